// Round 1
// baseline (92.970 us; speedup 1.0000x reference)
//
#include <hip/hip_runtime.h>

// LIF recurrence: mem = 0.9*mem + x; spike = (mem >= 1); record spike & mem;
// mem -= spike. T=20 steps, elementwise-independent -> one thread per float4.
//
// Output layout (concatenated flat, return order):
//   out[0          .. T*N-1]  = spike_trains  [T][64][8192]
//   out[T*N        .. 2*T*N-1]= membrane_pot  [T][64][8192]
//
// Numerics: forced mul-then-add rounding (__fmul_rn/__fadd_rn) to match the
// numpy fp32 reference exactly -- an FMA contraction can flip the >=1.0
// threshold by 1 ulp and produce absmax=1.0.

#define TSTEPS 20

__global__ __launch_bounds__(256) void
TemporalEncoding_57672820850797_kernel(const float4* __restrict__ x,
                                       float* __restrict__ out, int n4) {
    int i = blockIdx.x * blockDim.x + threadIdx.x;  // float4 index
    if (i >= n4) return;

    const float4 xv = x[i];
    float4* __restrict__ spikes = reinterpret_cast<float4*>(out);
    float4* __restrict__ mems   = reinterpret_cast<float4*>(out) + (size_t)TSTEPS * n4;

    float m0 = 0.f, m1 = 0.f, m2 = 0.f, m3 = 0.f;

#pragma unroll
    for (int t = 0; t < TSTEPS; ++t) {
        // mem = 0.9*mem + x, with separate rounding steps (no FMA contraction)
        m0 = __fadd_rn(__fmul_rn(0.9f, m0), xv.x);
        m1 = __fadd_rn(__fmul_rn(0.9f, m1), xv.y);
        m2 = __fadd_rn(__fmul_rn(0.9f, m2), xv.z);
        m3 = __fadd_rn(__fmul_rn(0.9f, m3), xv.w);

        float s0 = (m0 >= 1.0f) ? 1.0f : 0.0f;
        float s1 = (m1 >= 1.0f) ? 1.0f : 0.0f;
        float s2 = (m2 >= 1.0f) ? 1.0f : 0.0f;
        float s3 = (m3 >= 1.0f) ? 1.0f : 0.0f;

        spikes[(size_t)t * n4 + i] = make_float4(s0, s1, s2, s3);
        mems  [(size_t)t * n4 + i] = make_float4(m0, m1, m2, m3);

        // reset: mem -= spike*thr  (thr = 1.0, exact subtraction)
        m0 -= s0;
        m1 -= s1;
        m2 -= s2;
        m3 -= s3;
    }
}

extern "C" void kernel_launch(void* const* d_in, const int* in_sizes, int n_in,
                              void* d_out, int out_size, void* d_ws, size_t ws_size,
                              hipStream_t stream) {
    const float* x = (const float*)d_in[0];
    float* out = (float*)d_out;
    const int n = in_sizes[0];       // 64*8192 = 524288
    const int n4 = n / 4;            // 131072 float4 lanes
    const int block = 256;
    const int grid = (n4 + block - 1) / block;  // 512 blocks
    TemporalEncoding_57672820850797_kernel<<<grid, block, 0, stream>>>(
        (const float4*)x, out, n4);
}

// Round 2
// 90.160 us; speedup vs baseline: 1.0312x; 1.0312x over previous
//
#include <hip/hip_runtime.h>

// LIF recurrence: mem = 0.9*mem + x; spike = (mem >= 1); record spike & mem;
// mem -= spike. T=20 steps, elementwise-independent -> one thread per float4.
//
// Output layout (concatenated flat, return order):
//   out[0          .. T*N-1]   = spike_trains  [T][64][8192]
//   out[T*N        .. 2*T*N-1] = membrane_pot  [T][64][8192]
//
// R2 change: non-temporal stores for the write-once 84 MB output stream
// (bypass L2/L3 write-allocate). Numerics unchanged: forced mul-then-add
// rounding (__fmul_rn/__fadd_rn) to match numpy fp32 exactly -- FMA
// contraction can flip the >=1.0 threshold by 1 ulp (absmax=1.0).

#define TSTEPS 20

typedef float v4f __attribute__((ext_vector_type(4)));

__global__ __launch_bounds__(256) void
TemporalEncoding_57672820850797_kernel(const v4f* __restrict__ x,
                                       float* __restrict__ out, int n4) {
    int i = blockIdx.x * blockDim.x + threadIdx.x;  // float4 index
    if (i >= n4) return;

    const v4f xv = __builtin_nontemporal_load(&x[i]);
    v4f* __restrict__ spikes = reinterpret_cast<v4f*>(out) + i;
    v4f* __restrict__ mems   = reinterpret_cast<v4f*>(out) + (size_t)TSTEPS * n4 + i;

    float m0 = 0.f, m1 = 0.f, m2 = 0.f, m3 = 0.f;

#pragma unroll
    for (int t = 0; t < TSTEPS; ++t) {
        // mem = 0.9*mem + x, with separate rounding steps (no FMA contraction)
        m0 = __fadd_rn(__fmul_rn(0.9f, m0), xv.x);
        m1 = __fadd_rn(__fmul_rn(0.9f, m1), xv.y);
        m2 = __fadd_rn(__fmul_rn(0.9f, m2), xv.z);
        m3 = __fadd_rn(__fmul_rn(0.9f, m3), xv.w);

        float s0 = (m0 >= 1.0f) ? 1.0f : 0.0f;
        float s1 = (m1 >= 1.0f) ? 1.0f : 0.0f;
        float s2 = (m2 >= 1.0f) ? 1.0f : 0.0f;
        float s3 = (m3 >= 1.0f) ? 1.0f : 0.0f;

        v4f sv; sv.x = s0; sv.y = s1; sv.z = s2; sv.w = s3;
        v4f mv; mv.x = m0; mv.y = m1; mv.z = m2; mv.w = m3;
        __builtin_nontemporal_store(sv, spikes);
        __builtin_nontemporal_store(mv, mems);
        spikes += n4;
        mems   += n4;

        // reset: mem -= spike*thr  (thr = 1.0, exact subtraction)
        m0 -= s0;
        m1 -= s1;
        m2 -= s2;
        m3 -= s3;
    }
}

extern "C" void kernel_launch(void* const* d_in, const int* in_sizes, int n_in,
                              void* d_out, int out_size, void* d_ws, size_t ws_size,
                              hipStream_t stream) {
    const float* x = (const float*)d_in[0];
    float* out = (float*)d_out;
    const int n = in_sizes[0];       // 64*8192 = 524288
    const int n4 = n / 4;            // 131072 float4 lanes
    const int block = 256;
    const int grid = (n4 + block - 1) / block;  // 512 blocks
    TemporalEncoding_57672820850797_kernel<<<grid, block, 0, stream>>>(
        (const v4f*)x, out, n4);
}